// Round 10
// baseline (410.425 us; speedup 1.0000x reference)
//
#include <hip/hip_runtime.h>
#include <math.h>

// ---------------------------------------------------------------------------
// PCSQCNN: FRQI encode -> [QFT2D -> mux -> IQFT2D -> pool]^3 -> |.|^2 -> linear
//
// Global layout: S[b][X][f][Y] (float2), row base = ((b*128+X)*2+f)*128.
// Row passes: direct global<->register I/O. Column passes: staged via LDS.
// k2/k4 Y0 XCD-share swizzle (verified round 6).
//
// Round 10: AoS float2 LDS (b64 ds ops, ~2x bytes/cycle vs b32 per m134
// width scaling) + XOR bank-pair swizzle at float2 granularity:
//   pf(L,i) = L*128 + (i ^ (b4?6:0) ^ (b5?8:0) ^ (b6?3:0))
// GF(2) rank analysis: all ownership patterns used (S=1,2,4,8,16,32 at
// N=128/64/32, staged transpose, stride-2 f-pair, k5 reduce) map full-rank
// onto the 4 bank-pair bits -> every wave64 b64 op at its bank-slot minimum.
// Arithmetic/ownership/barriers byte-identical to verified rounds 7/9.
// ---------------------------------------------------------------------------

#define PI_F 3.14159265358979323846f
#define P_ 128               // line pitch (float2); swizzle is bijective 0..127

__device__ __forceinline__ float2 cmul(float2 a, float2 b) {
    return make_float2(a.x * b.x - a.y * b.y, a.x * b.y + a.y * b.x);
}
__device__ __forceinline__ float2 cadd(float2 a, float2 b) {
    return make_float2(a.x + b.x, a.y + b.y);
}
__device__ __forceinline__ float2 scl(float2 a, float s) {
    return make_float2(a.x * s, a.y * s);
}
// DIF butterfly: u' = u+v ; v' = (u-v)*w
__device__ __forceinline__ void bfly_dif(float2& u, float2& v, float2 w) {
    float tx = u.x - v.x, ty = u.y - v.y;
    u.x += v.x; u.y += v.y;
    v.x = tx * w.x - ty * w.y;
    v.y = tx * w.y + ty * w.x;
}
__device__ __forceinline__ void bfly_dif1(float2& u, float2& v) {
    float tx = u.x - v.x, ty = u.y - v.y;
    u.x += v.x; u.y += v.y;
    v.x = tx; v.y = ty;
}
// DIT inverse butterfly: t = v*conj(w); u' = u+t ; v' = u-t
__device__ __forceinline__ void bfly_dit(float2& u, float2& v, float2 w) {
    float tx = v.x * w.x + v.y * w.y, ty = v.y * w.x - v.x * w.y;
    v.x = u.x - tx; v.y = u.y - ty;
    u.x += tx; u.y += ty;
}
__device__ __forceinline__ void bfly_dit1(float2& u, float2& v) {
    float tx = v.x, ty = v.y;
    v.x = u.x - tx; v.y = u.y - ty;
    u.x += tx; u.y += ty;
}

constexpr int clog2(int v) { return v <= 1 ? 0 : 1 + clog2(v >> 1); }

// LDS address in float2 units: line L, idx 0..127, XOR bank-pair swizzle.
__device__ __forceinline__ int pf(int L, int idx) {
    int m = ((idx & 16) ? 6 : 0) ^ ((idx & 32) ? 8 : 0) ^ ((idx & 64) ? 3 : 0);
    return L * P_ + (idx ^ m);
}

// Ownership: segment size N (<=128), stride S. Thread j (0..31 per line) owns
// idx[q] = seg*N + 4S*(jj/S) + (jj%S) + S*q.  o = jj%S (twiddle low part).
template <int N, int S>
__device__ __forceinline__ void oidx(int j, int i[4], int& o) {
    constexpr int TPS = N / 4;
    constexpr int LT = clog2(TPS);
    int s = j >> LT;
    int jj = j & (TPS - 1);
    o = jj & (S - 1);
    int base = s * N + ((jj & ~(S - 1)) << 2) + o;
    i[0] = base; i[1] = base + S; i[2] = base + 2 * S; i[3] = base + 3 * S;
}

// Two DIF levels h=2S then h=S on r[0..3] (ownership stride S)
template <int S>
__device__ __forceinline__ void dif_pair(float2 r[4], int o, const float2* tw) {
    bfly_dif(r[0], r[2], tw[o * (32 / S)]);
    bfly_dif(r[1], r[3], tw[(o + S) * (32 / S)]);
    float2 wc = tw[o * (64 / S)];
    bfly_dif(r[0], r[1], wc);
    bfly_dif(r[2], r[3], wc);
}
// Two DIT levels h=S then h=2S
template <int S>
__device__ __forceinline__ void dit_pair(float2 r[4], int o, const float2* tw) {
    float2 wc = tw[o * (64 / S)];
    bfly_dit(r[0], r[1], wc);
    bfly_dit(r[2], r[3], wc);
    bfly_dit(r[0], r[2], tw[o * (32 / S)]);
    bfly_dit(r[1], r[3], tw[(o + S) * (32 / S)]);
}

// Wave-synchronous round trip (exchange within a 32-thread line = half wave).
template <int NW, int SW, int NR, int SR>
__device__ __forceinline__ int xchg(float2* buf, int L, int j, float2 r[4]) {
    int iw[4], ow;
    oidx<NW, SW>(j, iw, ow);
    buf[pf(L, iw[0])] = r[0]; buf[pf(L, iw[1])] = r[1];
    buf[pf(L, iw[2])] = r[2]; buf[pf(L, iw[3])] = r[3];
    __builtin_amdgcn_wave_barrier();
    int ir[4], orr;
    oidx<NR, SR>(j, ir, orr);
    r[0] = buf[pf(L, ir[0])]; r[1] = buf[pf(L, ir[1])];
    r[2] = buf[pf(L, ir[2])]; r[3] = buf[pf(L, ir[3])];
    __builtin_amdgcn_wave_barrier();
    return orr;
}

__device__ __forceinline__ void tw_init(float2* tw, int tid) {
    if (tid < 64) {
        float s, c;
        sincosf(-(2.0f * PI_F / 128.0f) * (float)tid, &s, &c);
        tw[tid] = make_float2(c, s);
    }
}

// ---------------------------------------------------------------------------
// K0: precompute multiplex U tables, pre-permuted by bit-reversal (unchanged).
// ---------------------------------------------------------------------------
__global__ __launch_bounds__(256) void k0_prep(const float* __restrict__ mux0,
                                               const float* __restrict__ mux1,
                                               const float* __restrict__ mux2,
                                               float2* __restrict__ U0,
                                               float2* __restrict__ U1,
                                               float2* __restrict__ U2) {
    int t = blockIdx.x * 256 + threadIdx.x;
    const float* src;
    float2* dst;
    if (t < 16384) {
        int xb = t >> 7, yb = t & 127;
        int rx = __brev((unsigned)xb) >> 25;
        int ry = __brev((unsigned)yb) >> 25;
        src = mux0 + ((size_t)rx * 128 + ry) * 3;
        dst = U0 + (size_t)t * 4;
    } else if (t < 32768) {
        int u = t - 16384;
        int yam = u & 63, xam = (u >> 6) & 63, cy = (u >> 12) & 1, cx = (u >> 13) & 1;
        int rx = __brev((unsigned)xam) >> 26;
        int ry = __brev((unsigned)yam) >> 26;
        src = mux1 + ((size_t)(((cx * 2 + cy) * 64 + rx) * 64 + ry)) * 3;
        dst = U1 + (size_t)u * 4;
    } else if (t < 36864) {
        int u = t - 32768;
        int yam = u & 31, xam = (u >> 5) & 31, cy = (u >> 10) & 1, cx = (u >> 11) & 1;
        int rx = __brev((unsigned)xam) >> 27;
        int ry = __brev((unsigned)yam) >> 27;
        src = mux2 + ((size_t)(((cx * 2 + cy) * 32 + rx) * 32 + ry)) * 3;
        dst = U2 + (size_t)u * 4;
    } else {
        return;
    }
    float ax = src[0], ay = src[1], az = src[2];
    float r = sqrtf(ax * ax + ay * ay + az * az + 1e-20f);
    float cr = cosf(r);
    float snr = sinf(r) / r;
    dst[0] = make_float2(cr, -az * snr);
    dst[1] = make_float2(-ay * snr, -ax * snr);
    dst[2] = make_float2(ay * snr, -ax * snr);
    dst[3] = make_float2(cr, az * snr);
}

// ---------------------------------------------------------------------------
// K1: FRQI encode + DIF_Y128. Lines L = row*2+f (4 X-rows x 2 f). Direct I/O.
// ---------------------------------------------------------------------------
__global__ __launch_bounds__(256) void k1_encode(const float* __restrict__ img,
                                                 float2* __restrict__ S) {
    __shared__ float2 A[8 * P_], B[8 * P_];
    __shared__ float2 tw[64];
    int tid = threadIdx.x;
    tw_init(tw, tid);
    int b = blockIdx.x >> 5;
    int X0 = (blockIdx.x & 31) * 4;
    int L = tid >> 5, j = tid & 31;
    int row = L >> 1, f = L & 1;
    const float* ip = img + ((size_t)(b * 128) + X0 + row) * 128;
    float2 r[4];
#pragma unroll
    for (int q = 0; q < 4; ++q) {
        float v = ip[j + 32 * q];
        float s, c;
        sincosf(0.5f * PI_F * v, &s, &c);
        float a = f ? s : c;
        r[q] = make_float2(a * (1.0f / 128.0f), 0.0f);  // S32 ownership, natural Y
    }
    __syncthreads();                        // tw visibility
    dif_pair<32>(r, j, tw);                 // h=64,32
    int o = xchg<128, 32, 128, 8>(A, L, j, r);
    dif_pair<8>(r, o, tw);                  // h=16,8
    o = xchg<128, 8, 128, 2>(B, L, j, r);
    dif_pair<2>(r, o, tw);                  // h=4,2
    o = xchg<128, 2, 128, 1>(A, L, j, r);
    bfly_dif1(r[0], r[1]); bfly_dif1(r[2], r[3]);  // h=1
    float2* op = S + ((size_t)((b * 128 + X0 + row) * 2 + f)) * 128 + 4 * j;
    float4* gp = (float4*)op;
    gp[0] = make_float4(r[0].x, r[0].y, r[1].x, r[1].y);
    gp[1] = make_float4(r[2].x, r[2].y, r[3].x, r[3].y);
}

// ---------------------------------------------------------------------------
// K2: column pass. FFT_X128 -> M0 -> IFFT_X128 -> FFT_X64. Lines L = f*4+yl.
// Y0 swizzled so same-XCD blocks share cache lines.
// ---------------------------------------------------------------------------
__global__ __launch_bounds__(256) void k2_col0(float2* __restrict__ S,
                                               const float2* __restrict__ U0) {
    __shared__ float2 A[8 * P_], B[8 * P_];
    __shared__ float2 tw[64];
    int tid = threadIdx.x;
    tw_init(tw, tid);
    int b = blockIdx.x >> 5;
    int s_ = blockIdx.x & 31;
    int Y0 = (((s_ & 7) << 2) | (s_ >> 3)) * 4;  // XCD-share swizzle
    {   // staged load: thread = (X, f), 4 consecutive Y (2x float4)
        int X = tid & 127, f = tid >> 7;
        const float4* gp = (const float4*)(S + ((size_t)((b * 128 + X) * 2 + f)) * 128 + Y0);
        float4 v0 = gp[0], v1 = gp[1];
        A[pf(f * 4 + 0, X)] = make_float2(v0.x, v0.y);
        A[pf(f * 4 + 1, X)] = make_float2(v0.z, v0.w);
        A[pf(f * 4 + 2, X)] = make_float2(v1.x, v1.y);
        A[pf(f * 4 + 3, X)] = make_float2(v1.z, v1.w);
    }
    __syncthreads();                              // staging is cross-wave
    int L = tid >> 5, j = tid & 31;
    float2 r[4];
    int o;
    {
        int ir[4];
        oidx<128, 32>(j, ir, o);
        r[0] = A[pf(L, ir[0])]; r[1] = A[pf(L, ir[1])];
        r[2] = A[pf(L, ir[2])]; r[3] = A[pf(L, ir[3])];
    }
    dif_pair<32>(r, o, tw);                       // FFT128 h=64,32
    o = xchg<128, 32, 128, 8>(B, L, j, r);
    dif_pair<8>(r, o, tw);                        // h=16,8
    o = xchg<128, 8, 128, 2>(A, L, j, r);
    dif_pair<2>(r, o, tw);                        // h=4,2
    {   // -> f-pair ownership (cross-wave section: real barriers)
        int iw[4], ow;
        oidx<128, 2>(j, iw, ow);
        B[pf(L, iw[0])] = r[0]; B[pf(L, iw[1])] = r[1];
        B[pf(L, iw[2])] = r[2]; B[pf(L, iw[3])] = r[3];
    }
    __syncthreads();
    int yl = tid >> 6, m2 = (tid & 63) * 2;
    r[0] = B[pf(yl, m2)];     r[1] = B[pf(4 + yl, m2)];
    r[2] = B[pf(yl, m2 + 1)]; r[3] = B[pf(4 + yl, m2 + 1)];
    bfly_dif1(r[0], r[2]); bfly_dif1(r[1], r[3]);  // FFT128 h=1 (per f)
    {   // M0 (table pre-permuted rev7 x rev7)
        const float2* U = U0 + ((size_t)m2 * 128 + (Y0 + yl)) * 4;
        float2 p0 = r[0], p1 = r[1];
        r[0] = cadd(cmul(U[0], p0), cmul(U[1], p1));
        r[1] = cadd(cmul(U[2], p0), cmul(U[3], p1));
        U = U0 + ((size_t)(m2 + 1) * 128 + (Y0 + yl)) * 4;
        p0 = r[2]; p1 = r[3];
        r[2] = cadd(cmul(U[0], p0), cmul(U[1], p1));
        r[3] = cadd(cmul(U[2], p0), cmul(U[3], p1));
    }
    bfly_dit1(r[0], r[2]); bfly_dit1(r[1], r[3]);  // IFFT128 h=1
    A[pf(yl, m2)] = r[0];     A[pf(4 + yl, m2)] = r[1];
    A[pf(yl, m2 + 1)] = r[2]; A[pf(4 + yl, m2 + 1)] = r[3];
    __syncthreads();
    {
        int ir[4];
        oidx<128, 2>(j, ir, o);
        r[0] = A[pf(L, ir[0])]; r[1] = A[pf(L, ir[1])];
        r[2] = A[pf(L, ir[2])]; r[3] = A[pf(L, ir[3])];
    }
    dit_pair<2>(r, o, tw);                        // h=2,4
    o = xchg<128, 2, 128, 8>(B, L, j, r);
    dit_pair<8>(r, o, tw);                        // h=8,16
    o = xchg<128, 8, 128, 32>(A, L, j, r);
    dit_pair<32>(r, o, tw);                       // h=32,64 -> X natural
    {   // fused FFT64 h=32 (segments (r0,r1),(r2,r3))
        float2 w = tw[2 * o];
        bfly_dif(r[0], r[1], w); bfly_dif(r[2], r[3], w);
    }
    o = xchg<128, 32, 64, 8>(B, L, j, r);
    dif_pair<8>(r, o, tw);                        // FFT64 h=16,8
    o = xchg<64, 8, 64, 2>(A, L, j, r);
    dif_pair<2>(r, o, tw);                        // h=4,2
    o = xchg<64, 2, 64, 1>(B, L, j, r);
    bfly_dif1(r[0], r[1]); bfly_dif1(r[2], r[3]); // h=1
    {
        int iw[4], ow;
        oidx<64, 1>(j, iw, ow);
        const float sc = 1.0f / 128.0f;           // IFFT128 norm
        A[pf(L, iw[0])] = scl(r[0], sc); A[pf(L, iw[1])] = scl(r[1], sc);
        A[pf(L, iw[2])] = scl(r[2], sc); A[pf(L, iw[3])] = scl(r[3], sc);
    }
    __syncthreads();                              // staged store is cross-wave
    {   // staged store
        int X = tid & 127, f = tid >> 7;
        float2 e0 = A[pf(f * 4 + 0, X)], e1 = A[pf(f * 4 + 1, X)];
        float2 e2 = A[pf(f * 4 + 2, X)], e3 = A[pf(f * 4 + 3, X)];
        float4* gp = (float4*)(S + ((size_t)((b * 128 + X) * 2 + f)) * 128 + Y0);
        gp[0] = make_float4(e0.x, e0.y, e1.x, e1.y);
        gp[1] = make_float4(e2.x, e2.y, e3.x, e3.y);
    }
}

// ---------------------------------------------------------------------------
// K3: row pass. IFFT_Y128 -> FFT_Y64 -> M1 -> IFFT_Y64 -> FFT_Y32.
// Lines L = row*2+f. Direct global I/O.
// ---------------------------------------------------------------------------
__global__ __launch_bounds__(256) void k3_row1(float2* __restrict__ S,
                                               const float2* __restrict__ U1) {
    __shared__ float2 A[8 * P_], B[8 * P_];
    __shared__ float2 tw[64];
    int tid = threadIdx.x;
    tw_init(tw, tid);
    int b = blockIdx.x >> 5;
    int X0 = (blockIdx.x & 31) * 4;
    int L = tid >> 5, j = tid & 31;
    int row = L >> 1, f = L & 1;
    float2* gl = S + ((size_t)((b * 128 + X0 + row) * 2 + f)) * 128;
    float2 r[4];
    {
        const float4* gp = (const float4*)(gl + 4 * j);
        float4 v0 = gp[0], v1 = gp[1];
        r[0] = make_float2(v0.x, v0.y); r[1] = make_float2(v0.z, v0.w);
        r[2] = make_float2(v1.x, v1.y); r[3] = make_float2(v1.z, v1.w);
    }
    __syncthreads();                              // tw visibility
    dit_pair<1>(r, 0, tw);                        // IFFT128 h=1,2
    int o = xchg<128, 1, 128, 4>(A, L, j, r);
    dit_pair<4>(r, o, tw);                        // h=4,8
    o = xchg<128, 4, 128, 16>(B, L, j, r);
    dit_pair<16>(r, o, tw);                       // h=16,32
    o = xchg<128, 16, 128, 32>(A, L, j, r);
    bfly_dit(r[0], r[2], tw[o]);                  // h=64 -> Y natural
    bfly_dit(r[1], r[3], tw[o + 32]);
    {   // fused FFT64 h=32
        float2 w = tw[2 * o];
        bfly_dif(r[0], r[1], w); bfly_dif(r[2], r[3], w);
    }
    o = xchg<128, 32, 64, 8>(B, L, j, r);
    dif_pair<8>(r, o, tw);                        // FFT64 h=16,8
    o = xchg<64, 8, 64, 2>(A, L, j, r);
    dif_pair<2>(r, o, tw);                        // h=4,2
    {   // -> f-pair ownership (cross-wave section: real barriers)
        int iw[4], ow;
        oidx<64, 2>(j, iw, ow);
        B[pf(L, iw[0])] = r[0]; B[pf(L, iw[1])] = r[1];
        B[pf(L, iw[2])] = r[2]; B[pf(L, iw[3])] = r[3];
    }
    __syncthreads();
    int row2 = tid >> 6, m2 = (tid & 63) * 2;
    r[0] = B[pf(row2 * 2, m2)];
    r[1] = B[pf(row2 * 2 + 1, m2)];
    r[2] = B[pf(row2 * 2, m2 + 1)];
    r[3] = B[pf(row2 * 2 + 1, m2 + 1)];
    bfly_dif1(r[0], r[2]); bfly_dif1(r[1], r[3]);  // FFT64 h=1 (per f)
    {   // M1: cx = X>>6, xam = X&63 (rev6 in table); same for Y
        int X = X0 + row2;
        int cx = X >> 6, xam = X & 63;
        int cy0 = m2 >> 6, yam0 = m2 & 63;
        const float2* U =
            U1 + ((size_t)((((cx << 1) | cy0) << 6 | xam) << 6 | yam0)) * 4;
        float2 p0 = r[0], p1 = r[1];
        r[0] = cadd(cmul(U[0], p0), cmul(U[1], p1));
        r[1] = cadd(cmul(U[2], p0), cmul(U[3], p1));
        int cy1 = (m2 + 1) >> 6, yam1 = (m2 + 1) & 63;
        U = U1 + ((size_t)((((cx << 1) | cy1) << 6 | xam) << 6 | yam1)) * 4;
        p0 = r[2]; p1 = r[3];
        r[2] = cadd(cmul(U[0], p0), cmul(U[1], p1));
        r[3] = cadd(cmul(U[2], p0), cmul(U[3], p1));
    }
    bfly_dit1(r[0], r[2]); bfly_dit1(r[1], r[3]);  // IFFT64 h=1
    A[pf(row2 * 2, m2)] = r[0];
    A[pf(row2 * 2 + 1, m2)] = r[1];
    A[pf(row2 * 2, m2 + 1)] = r[2];
    A[pf(row2 * 2 + 1, m2 + 1)] = r[3];
    __syncthreads();
    {
        int ir[4];
        oidx<64, 2>(j, ir, o);
        r[0] = A[pf(L, ir[0])]; r[1] = A[pf(L, ir[1])];
        r[2] = A[pf(L, ir[2])]; r[3] = A[pf(L, ir[3])];
    }
    dit_pair<2>(r, o, tw);                        // IFFT64 h=2,4
    o = xchg<64, 2, 64, 8>(B, L, j, r);
    dit_pair<8>(r, o, tw);                        // h=8,16
    o = xchg<64, 8, 64, 16>(A, L, j, r);
    bfly_dit(r[0], r[2], tw[2 * o]);              // IFFT64 h=32 -> natural
    bfly_dit(r[1], r[3], tw[2 * o + 32]);
    {   // fused FFT32 h=16
        float2 w = tw[4 * o];
        bfly_dif(r[0], r[1], w); bfly_dif(r[2], r[3], w);
    }
    o = xchg<64, 16, 32, 4>(B, L, j, r);
    dif_pair<4>(r, o, tw);                        // FFT32 h=8,4
    o = xchg<32, 4, 32, 1>(A, L, j, r);
    dif_pair<1>(r, 0, tw);                        // h=2,1
    {
        int iw[4], ow;
        oidx<32, 1>(j, iw, ow);
        const float sc = 1.0f / 8192.0f;          // IFFT128 * IFFT64 norms
        float4* gp = (float4*)(gl + iw[0]);
        gp[0] = make_float4(r[0].x * sc, r[0].y * sc, r[1].x * sc, r[1].y * sc);
        gp[1] = make_float4(r[2].x * sc, r[2].y * sc, r[3].x * sc, r[3].y * sc);
    }
}

// ---------------------------------------------------------------------------
// K4: column pass. IFFT_X64 -> FFT_X32 -> M2 -> IFFT_X32. Lines L = f*4+yl.
// Y0 swizzled (same scheme as K2).
// ---------------------------------------------------------------------------
__global__ __launch_bounds__(256) void k4_col2(float2* __restrict__ S,
                                               const float2* __restrict__ U2) {
    __shared__ float2 A[8 * P_], B[8 * P_];
    __shared__ float2 tw[64];
    int tid = threadIdx.x;
    tw_init(tw, tid);
    int b = blockIdx.x >> 5;
    int s_ = blockIdx.x & 31;
    int Y0 = (((s_ & 7) << 2) | (s_ >> 3)) * 4;  // XCD-share swizzle
    {
        int X = tid & 127, f = tid >> 7;
        const float4* gp = (const float4*)(S + ((size_t)((b * 128 + X) * 2 + f)) * 128 + Y0);
        float4 v0 = gp[0], v1 = gp[1];
        A[pf(f * 4 + 0, X)] = make_float2(v0.x, v0.y);
        A[pf(f * 4 + 1, X)] = make_float2(v0.z, v0.w);
        A[pf(f * 4 + 2, X)] = make_float2(v1.x, v1.y);
        A[pf(f * 4 + 3, X)] = make_float2(v1.z, v1.w);
    }
    __syncthreads();                              // staging is cross-wave
    int L = tid >> 5, j = tid & 31;
    float2 r[4];
    int o;
    {
        int ir[4];
        oidx<64, 1>(j, ir, o);
        r[0] = A[pf(L, ir[0])]; r[1] = A[pf(L, ir[1])];
        r[2] = A[pf(L, ir[2])]; r[3] = A[pf(L, ir[3])];
    }
    dit_pair<1>(r, 0, tw);                        // IFFT64 h=1,2
    o = xchg<64, 1, 64, 4>(B, L, j, r);
    dit_pair<4>(r, o, tw);                        // h=4,8
    o = xchg<64, 4, 64, 16>(A, L, j, r);
    dit_pair<16>(r, o, tw);                       // h=16,32 -> natural in 64
    {   // fused FFT32 h=16
        float2 w = tw[4 * o];
        bfly_dif(r[0], r[1], w); bfly_dif(r[2], r[3], w);
    }
    o = xchg<64, 16, 32, 4>(B, L, j, r);
    dif_pair<4>(r, o, tw);                        // FFT32 h=8,4
    o = xchg<32, 4, 32, 1>(A, L, j, r);
    dif_pair<1>(r, 0, tw);                        // h=2,1
    {   // -> f-pair ownership (cross-wave section: real barriers)
        int iw[4], ow;
        oidx<32, 1>(j, iw, ow);
        B[pf(L, iw[0])] = r[0]; B[pf(L, iw[1])] = r[1];
        B[pf(L, iw[2])] = r[2]; B[pf(L, iw[3])] = r[3];
    }
    __syncthreads();
    int yl = tid >> 6, m2 = (tid & 63) * 2;
    r[0] = B[pf(yl, m2)];     r[1] = B[pf(4 + yl, m2)];
    r[2] = B[pf(yl, m2 + 1)]; r[3] = B[pf(4 + yl, m2 + 1)];
    {   // M2: cx = (X>>5)&1, xam = X&31 (rev5 in table); Ym = Y0+yl
        int Ym = Y0 + yl;
        int cy = (Ym >> 5) & 1, yam = Ym & 31;
        int cx = (m2 >> 5) & 1, xam = m2 & 31;
        const float2* U =
            U2 + ((size_t)((((cx << 1) | cy) << 5 | xam) << 5 | yam)) * 4;
        float2 p0 = r[0], p1 = r[1];
        r[0] = cadd(cmul(U[0], p0), cmul(U[1], p1));
        r[1] = cadd(cmul(U[2], p0), cmul(U[3], p1));
        int X1 = m2 + 1;
        cx = (X1 >> 5) & 1; xam = X1 & 31;
        U = U2 + ((size_t)((((cx << 1) | cy) << 5 | xam) << 5 | yam)) * 4;
        p0 = r[2]; p1 = r[3];
        r[2] = cadd(cmul(U[0], p0), cmul(U[1], p1));
        r[3] = cadd(cmul(U[2], p0), cmul(U[3], p1));
    }
    bfly_dit1(r[0], r[2]); bfly_dit1(r[1], r[3]);  // IFFT32 h=1
    A[pf(yl, m2)] = r[0];     A[pf(4 + yl, m2)] = r[1];
    A[pf(yl, m2 + 1)] = r[2]; A[pf(4 + yl, m2 + 1)] = r[3];
    __syncthreads();
    {
        int ir[4];
        oidx<32, 2>(j, ir, o);
        r[0] = A[pf(L, ir[0])]; r[1] = A[pf(L, ir[1])];
        r[2] = A[pf(L, ir[2])]; r[3] = A[pf(L, ir[3])];
    }
    dit_pair<2>(r, o, tw);                        // IFFT32 h=2,4
    o = xchg<32, 2, 32, 8>(B, L, j, r);
    dit_pair<8>(r, o, tw);                        // h=8,16 -> X natural
    {
        int iw[4], ow;
        oidx<32, 8>(j, iw, ow);
        const float sc = 1.0f / 2048.0f;          // IFFT64 * IFFT32 norms
        A[pf(L, iw[0])] = scl(r[0], sc); A[pf(L, iw[1])] = scl(r[1], sc);
        A[pf(L, iw[2])] = scl(r[2], sc); A[pf(L, iw[3])] = scl(r[3], sc);
    }
    __syncthreads();                              // staged store is cross-wave
    {
        int X = tid & 127, f = tid >> 7;
        float2 e0 = A[pf(f * 4 + 0, X)], e1 = A[pf(f * 4 + 1, X)];
        float2 e2 = A[pf(f * 4 + 2, X)], e3 = A[pf(f * 4 + 3, X)];
        float4* gp = (float4*)(S + ((size_t)((b * 128 + X) * 2 + f)) * 128 + Y0);
        gp[0] = make_float4(e0.x, e0.y, e1.x, e1.y);
        gp[1] = make_float4(e2.x, e2.y, e3.x, e3.y);
    }
}

// ---------------------------------------------------------------------------
// K5: row pass. IFFT_Y32 + |.|^2 summed over xc (4 rows) and yc (4 segs).
// Block = (b, xa): rows X = xa + {0,32,64,96}. Lines L = row*2+f.
// ---------------------------------------------------------------------------
__global__ __launch_bounds__(256) void k5_prob(const float2* __restrict__ S,
                                               float* __restrict__ prob) {
    __shared__ float2 A[8 * P_], B[8 * P_];
    __shared__ float2 tw[64];
    int tid = threadIdx.x;
    tw_init(tw, tid);
    int b = blockIdx.x >> 5;
    int xa = blockIdx.x & 31;
    int L = tid >> 5, j = tid & 31;
    int row = L >> 1, f = L & 1;
    const float2* gl = S + ((size_t)((b * 128 + xa + 32 * row) * 2 + f)) * 128;
    float2 r[4];
    int o;
    int i0[4];
    oidx<32, 1>(j, i0, o);
    {
        const float4* gp = (const float4*)(gl + i0[0]);
        float4 v0 = gp[0], v1 = gp[1];
        r[0] = make_float2(v0.x, v0.y); r[1] = make_float2(v0.z, v0.w);
        r[2] = make_float2(v1.x, v1.y); r[3] = make_float2(v1.z, v1.w);
    }
    __syncthreads();                              // tw visibility
    dit_pair<1>(r, 0, tw);                        // IFFT32 h=1,2
    o = xchg<32, 1, 32, 4>(A, L, j, r);
    dit_pair<4>(r, o, tw);                        // h=4,8
    o = xchg<32, 4, 32, 8>(B, L, j, r);
    bfly_dit(r[0], r[2], tw[4 * o]);              // h=16 -> Y natural
    bfly_dit(r[1], r[3], tw[4 * o + 32]);
    {
        int iw[4], ow;
        oidx<32, 8>(j, iw, ow);
        A[pf(L, iw[0])] = r[0]; A[pf(L, iw[1])] = r[1];
        A[pf(L, iw[2])] = r[2]; A[pf(L, iw[3])] = r[3];
    }
    __syncthreads();                              // final reduce is cross-wave
    if (tid < 64) {
        int ya = tid >> 1, ff = tid & 1;
        float s = 0.0f;
        for (int rr = 0; rr < 4; ++rr)
            for (int yc = 0; yc < 4; ++yc) {
                float2 v = A[pf(rr * 2 + ff, yc * 32 + ya)];
                s += v.x * v.x + v.y * v.y;
            }
        // remaining norm: (1/32)^2 for IFFT_Y32 inside |.|^2
        prob[((size_t)(b * 32 + xa) * 32 + ya) * 2 + ff] = s * (1.0f / 1024.0f);
    }
}

// ---------------------------------------------------------------------------
// K6: linear head, wave-shuffle reduction.
// ---------------------------------------------------------------------------
__global__ __launch_bounds__(256) void k6_linear(const float* __restrict__ prob,
                                                 const float* __restrict__ W,
                                                 const float* __restrict__ bv,
                                                 float* __restrict__ out) {
    __shared__ float red[40];
    int b = blockIdx.x;
    int tid = threadIdx.x;
    float acc[10];
#pragma unroll
    for (int c = 0; c < 10; ++c) acc[c] = 0.0f;
    for (int j = tid; j < 2048; j += 256) {
        float p = prob[(size_t)b * 2048 + j];
#pragma unroll
        for (int c = 0; c < 10; ++c) acc[c] += p * W[c * 2048 + j];
    }
    int wv = tid >> 6, ln = tid & 63;
#pragma unroll
    for (int c = 0; c < 10; ++c) {
        float s = acc[c];
        for (int off = 32; off > 0; off >>= 1) s += __shfl_down(s, off);
        if (ln == 0) red[wv * 10 + c] = s;
    }
    __syncthreads();
    if (tid < 10)
        out[b * 10 + tid] =
            red[tid] + red[10 + tid] + red[20 + tid] + red[30 + tid] + bv[tid];
}

// ---------------------------------------------------------------------------
extern "C" void kernel_launch(void* const* d_in, const int* in_sizes, int n_in,
                              void* d_out, int out_size, void* d_ws,
                              size_t ws_size, hipStream_t stream) {
    const float* images = (const float*)d_in[0];
    const float* mux0 = (const float*)d_in[1];
    const float* mux1 = (const float*)d_in[2];
    const float* mux2 = (const float*)d_in[3];
    const float* W = (const float*)d_in[4];
    const float* bv = (const float*)d_in[5];
    float* out = (float*)d_out;

    float2* ws0 = (float2*)d_ws;
    const size_t STATE_F2 = (size_t)512 * 128 * 128 * 2;  // 16,777,216
    float2* S = ws0;
    float2* U0 = ws0 + STATE_F2;
    float2* U1 = U0 + 65536;
    float2* U2 = U1 + 65536;
    float* prob = (float*)(U2 + 16384);
    const size_t needed =
        (STATE_F2 + 65536 + 65536 + 16384) * sizeof(float2) +
        (size_t)512 * 2048 * sizeof(float);
    if (ws_size < needed) return;

    k0_prep<<<144, 256, 0, stream>>>(mux0, mux1, mux2, U0, U1, U2);
    k1_encode<<<16384, 256, 0, stream>>>(images, S);
    k2_col0<<<16384, 256, 0, stream>>>(S, U0);
    k3_row1<<<16384, 256, 0, stream>>>(S, U1);
    k4_col2<<<16384, 256, 0, stream>>>(S, U2);
    k5_prob<<<16384, 256, 0, stream>>>(S, prob);
    k6_linear<<<512, 256, 0, stream>>>(prob, W, bv, out);
}